// Round 1
// baseline (202.057 us; speedup 1.0000x reference)
//
#include <hip/hip_runtime.h>

// VQ-VAE loss: B=2, Q=64, K=512, N=1024, C=256, STRIDE=64, Nw=N*64-1=65535
//
// reference = mean_{b,t} [ logsoftmax(quant_pred)[b, tgt[b,t], t]
//                          + 1.25 * min_k sum_q (ze[b,q,t/64] - emb[k,t/64])^2 ]
//
// min_k sum_q (v_q - e)^2 = S2 - 2 e S1 + Q e^2  with S1=sum_q v, S2=sum_q v^2.

#define QQ   64
#define NN   1024
#define KK   512
#define CLS  256
#define NW   65535

// ---------------------------------------------------------------------------
// Kernel A: per (b,n) compute 1.25 * min_k cost into workspace; zero d_out.
// grid = B*N = 2048 blocks, 64 threads (1 wave). lane = q for the sums,
// lane strided over k for the min. ze/emb are tiny (0.5/2 MB) -> L2 resident.
// ---------------------------------------------------------------------------
__global__ __launch_bounds__(64) void vq_l2min_kernel(
        const float* __restrict__ ze,
        const float* __restrict__ emb,
        float* __restrict__ l2ws,
        float* __restrict__ out) {
    int bn = blockIdx.x;            // b*NN + n
    int b  = bn >> 10;
    int n  = bn & (NN - 1);
    int lane = threadIdx.x;

    // S1, S2 over q (lane = q), butterfly reduce so all lanes hold the sums
    float v  = ze[(size_t)(b * QQ + lane) * NN + n];
    float s1 = v, s2 = v * v;
    #pragma unroll
    for (int m = 32; m >= 1; m >>= 1) {
        s1 += __shfl_xor(s1, m, 64);
        s2 += __shfl_xor(s2, m, 64);
    }

    // min over k: lane handles k = lane + 64*j
    float best = 3.4e38f;
    float n2s1 = -2.0f * s1;
    #pragma unroll
    for (int j = 0; j < KK / 64; ++j) {
        float e = emb[(size_t)(lane + 64 * j) * NN + n];
        float c = fmaf(e, fmaf((float)QQ, e, n2s1), s2);
        best = fminf(best, c);
    }
    #pragma unroll
    for (int m = 32; m >= 1; m >>= 1)
        best = fminf(best, __shfl_xor(best, m, 64));

    if (lane == 0) l2ws[bn] = 1.25f * best;     // l2 + 0.25*commit
    if (bn == 0 && lane == 0) out[0] = 0.0f;    // zero accumulator (runs before B)
}

// ---------------------------------------------------------------------------
// Kernel B: streaming online-logsumexp over the class dim of quant_pred,
// target gather in the same pass, grid-sum via block reduce + atomicAdd.
// One thread per wav position t; lanes along t -> coalesced dword loads
// (class stride 65535 is odd, so no 16B vectorization is possible).
// grid = B * 65536 / 256 = 512 blocks x 256 threads = 2048 waves (8/CU).
// ---------------------------------------------------------------------------
__global__ __launch_bounds__(256) void vq_lse_kernel(
        const float* __restrict__ qp,
        const int*   __restrict__ tgt,
        const float* __restrict__ l2ws,
        float* __restrict__ out) {
    int g = blockIdx.x * 256 + threadIdx.x;
    int b = g >> 16;
    int t = g & 0xFFFF;

    float contrib = 0.0f;
    if (t < NW) {
        const float* p = qp + (size_t)b * CLS * NW + t;
        int   tg = tgt[(size_t)b * NW + t];
        float m = -3.4e38f, s = 0.0f, tv = 0.0f;
        #pragma unroll 4
        for (int c = 0; c < CLS; c += 4) {
            float x0 = p[(size_t)(c + 0) * NW];
            float x1 = p[(size_t)(c + 1) * NW];
            float x2 = p[(size_t)(c + 2) * NW];
            float x3 = p[(size_t)(c + 3) * NW];
            if (tg == c + 0) tv = x0;
            if (tg == c + 1) tv = x1;
            if (tg == c + 2) tv = x2;
            if (tg == c + 3) tv = x3;
            // tree-merge of 4 (4 exps) + online merge (2 exps) = 1.5 exp/elem
            float m01 = fmaxf(x0, x1), m23 = fmaxf(x2, x3);
            float m4  = fmaxf(m01, m23);
            float s4  = __expf(x0 - m4) + __expf(x1 - m4)
                      + __expf(x2 - m4) + __expf(x3 - m4);
            float nm  = fmaxf(m, m4);
            s = s * __expf(m - nm) + s4 * __expf(m4 - nm);
            m = nm;
        }
        float lse = m + __logf(s);
        contrib = tv - lse + l2ws[b * NN + (t >> 6)];
    }

    // wave butterfly reduce, then cross-wave via LDS, one atomic per block
    #pragma unroll
    for (int msk = 32; msk >= 1; msk >>= 1)
        contrib += __shfl_xor(contrib, msk, 64);

    __shared__ float part[4];
    int lane = threadIdx.x & 63, wv = threadIdx.x >> 6;
    if (lane == 0) part[wv] = contrib;
    __syncthreads();
    if (threadIdx.x == 0) {
        float blk = part[0] + part[1] + part[2] + part[3];
        atomicAdd(out, blk * (1.0f / 131070.0f));   // mean over B*Nw
    }
}

extern "C" void kernel_launch(void* const* d_in, const int* in_sizes, int n_in,
                              void* d_out, int out_size, void* d_ws, size_t ws_size,
                              hipStream_t stream) {
    const float* quant_pred = (const float*)d_in[0];   // (B, 256, 65535) fp32
    const float* ze         = (const float*)d_in[1];   // (B, 64, 1024)   fp32
    const float* emb        = (const float*)d_in[2];   // (512, 1024)     fp32
    const int*   target     = (const int*)  d_in[3];   // (B, 1, 65535)   int32
    float* out  = (float*)d_out;                       // scalar fp32
    float* l2ws = (float*)d_ws;                        // 2048 floats (8 KB)

    vq_l2min_kernel<<<2 * NN, 64, 0, stream>>>(ze, emb, l2ws, out);
    vq_lse_kernel<<<512, 256, 0, stream>>>(quant_pred, target, l2ws, out);
}